// Round 11
// baseline (1927.217 us; speedup 1.0000x reference)
//
#include <hip/hip_runtime.h>
#include <math.h>

#define BB    256
#define NN_   128
#define ZD    64
#define RD    128
#define HID   256
#define NSTEPS 50
#define NT    16
#define NTILES 8
#define TPB   1024
#define PADD  258   // f64 row stride

// ---------- fast f64-accuracy exp/sigmoid/gelu (no libm, no f64 divide) ----------
__device__ __forceinline__ double fast_exp_d(double x) {
    const double L2E   = 1.44269504088896340736;
    const double LN2HI = 6.93147180369123816490e-01;
    const double LN2LO = 1.90821492927058770002e-10;
    const double MAGIC = 6755399441055744.0;           // 1.5*2^52
    double vn = fma(x, L2E, MAGIC);
    int ni = __double2loint(vn);
    double n = vn - MAGIC;
    double r = fma(n, -LN2HI, x);
    r = fma(n, -LN2LO, r);
    double p = 2.50521083854417187751e-08;
    p = fma(p, r, 2.75573192239858906526e-07);
    p = fma(p, r, 2.75573192239858906526e-06);
    p = fma(p, r, 2.48015873015873015873e-05);
    p = fma(p, r, 1.98412698412698412698e-04);
    p = fma(p, r, 1.38888888888888888889e-03);
    p = fma(p, r, 8.33333333333333333333e-03);
    p = fma(p, r, 4.16666666666666666667e-02);
    p = fma(p, r, 1.66666666666666666667e-01);
    p = fma(p, r, 0.5);
    p = fma(p, r, 1.0);
    p = fma(p, r, 1.0);
    return p * __hiloint2double((1023 + ni) << 20, 0);
}

__device__ __forceinline__ double sigmoid_d(double w) {
    double wc = fmin(fmax(w, -60.0), 60.0);
    double e = fast_exp_d(-wc);
    double d = 1.0 + e;
    float r0 = __builtin_amdgcn_rcpf((float)d);
    double y = (double)r0;
    y = fma(y, fma(-d, y, 1.0), y);
    y = fma(y, fma(-d, y, 1.0), y);
    return y;
}

__device__ __forceinline__ double gelu_d(double x) {
    const double c2 = 1.59576912160573071176;
    double w = c2 * x * fma(0.044715, x * x, 1.0);
    return x * sigmoid_d(w);
}

__device__ __forceinline__ void gelu_both_d(double x, double& h, double& gp) {
    const double c  = 0.79788456080286535588;
    const double a  = 0.044715;
    double x2 = x * x;
    double w  = (2.0 * c) * x * fma(a, x2, 1.0);
    double hp = sigmoid_d(w);
    h = x * hp;
    double s = hp * (1.0 - hp);
    gp = fma(x * s, (2.0 * c) * fma(3.0 * a, x2, 1.0), hp);
}

// ---------- dynamic LDS layout (~154 KB) ----------
struct Smem {
    double h_t[NT][PADD];        // decode hidden tile (f64)      33.0 KB
    float  wd2t_f[8][PADD];      // Wd2^T, B-phase layout          8.3 KB
    float  wd2tq[8][8][33];      // Wd2, M-phase layout [q][yd][i] 8.4 KB
    double z_ds[ZD];
    double hb_ds[HID];           // pooled / drift hidden
    double scratch4[4][HID];     // A-partials / S-partials        8 KB
    double pmgz[1024];           // zdot partials / gzp[16][64]    8 KB (aliased)
    double res_r[NT][8];         // residual tile / r_d[128] alias
    double bp_d[16][ZD];         // drift-out partials             8 KB
    double bd2_d[8];
    double bb2_d[ZD];
    double hbt_s[HID];           // step-invariant drift-hidden base
    double wbt_s[HID];           // Wb1 t-row
    float  bd1_s[HID];
    float  x_s[NN_][8];
    float  y_s[NN_][8];
    float  m_s[NN_];
    __align__(16) float4 wd1z4[HID][16];   // Wd1 z-block, swizzled  64 KB
};

// r10 lesson: the fused M+R's w-read rotation dd=(d+2q) was 4-way bank
// conflicted (52.8M conflict cycles). Fix: dd=(d+q) for h (conflict-free,
// 4((nn+d+q)&7)), and a dedicated M-layout copy wd2tq[q][yd][33] whose bank
// (8q+yd+2dd) mod 32 is pairwise-distinct across all lane pairs (verified
// for every q-offset). zdot partials aliased into pmgz to pay for it.
__global__ void __launch_bounds__(TPB)
nets_sampler_kernel(
    const float* __restrict__ x_ctx, const float* __restrict__ y_ctx,
    const float* __restrict__ mask,  const float* __restrict__ z0,
    const float* __restrict__ noise,
    const float* __restrict__ We1, const float* __restrict__ be1,
    const float* __restrict__ We2, const float* __restrict__ be2,
    const float* __restrict__ Wd1, const float* __restrict__ bd1,
    const float* __restrict__ Wd2, const float* __restrict__ bd2,
    const float* __restrict__ Wb1, const float* __restrict__ bb1,
    const float* __restrict__ Wb2, const float* __restrict__ bb2,
    float* __restrict__ out)
{
    extern __shared__ char smem_raw[];
    Smem& sm = *reinterpret_cast<Smem*>(smem_raw);

    const int b   = blockIdx.x;
    const int tid = threadIdx.x;
    const int j   = tid & 255;       // hidden column
    const int q2  = tid >> 8;        // quarter (0..3)
    const int du_k = tid & 63, du_c = tid >> 6;   // 64x16 partition
    double* r_d = &sm.res_r[0][0];   // alias (pre-loop only)

    // ---------------- loads ----------------
    if (tid < 256) {
        reinterpret_cast<float4*>(&sm.x_s[0][0])[tid] =
            reinterpret_cast<const float4*>(x_ctx + (size_t)b * NN_ * 8)[tid];
        reinterpret_cast<float4*>(&sm.y_s[0][0])[tid] =
            reinterpret_cast<const float4*>(y_ctx + (size_t)b * NN_ * 8)[tid];
        sm.bd1_s[j] = bd1[j];
        float4 a0 = reinterpret_cast<const float4*>(Wd2 + (size_t)j * 8)[0];
        float4 a1 = reinterpret_cast<const float4*>(Wd2 + (size_t)j * 8)[1];
        sm.wd2t_f[0][j] = a0.x; sm.wd2t_f[1][j] = a0.y;
        sm.wd2t_f[2][j] = a0.z; sm.wd2t_f[3][j] = a0.w;
        sm.wd2t_f[4][j] = a1.x; sm.wd2t_f[5][j] = a1.y;
        sm.wd2t_f[6][j] = a1.z; sm.wd2t_f[7][j] = a1.w;
        const int wq = j >> 5, wi = j & 31;      // M-layout copy
        sm.wd2tq[wq][0][wi] = a0.x; sm.wd2tq[wq][1][wi] = a0.y;
        sm.wd2tq[wq][2][wi] = a0.z; sm.wd2tq[wq][3][wi] = a0.w;
        sm.wd2tq[wq][4][wi] = a1.x; sm.wd2tq[wq][5][wi] = a1.y;
        sm.wd2tq[wq][6][wi] = a1.z; sm.wd2tq[wq][7][wi] = a1.w;
    }
    if (tid < NN_) sm.m_s[tid] = mask[(size_t)b * NN_ + tid];
    if (tid < ZD) {
        sm.z_ds[tid]  = (double)z0[(size_t)b * ZD + tid];
        sm.bb2_d[tid] = (double)bb2[tid];
    }
    if (tid < 8) sm.bd2_d[tid] = (double)bd2[tid];

    // Wd1 z-block -> swizzled LDS
#pragma unroll
    for (int kk = 0; kk < 16; kk++) {
        const int k = q2 * 16 + kk;
        const float v = Wd1[(8 + k) * HID + j];
        reinterpret_cast<float*>(&sm.wd1z4[j][0])[4 * ((k >> 2) ^ (j & 15)) + (k & 3)] = v;
    }

    float wd1x[8];                       // Wd1 x-rows, column j (exact f32)
#pragma unroll
    for (int k = 0; k < 8; k++) wd1x[k] = Wd1[k * HID + j];

    __syncthreads();

    // ---------------- encoder (once, f64) ----------------
    if (tid < 256) {
        float we1r[16];
#pragma unroll
        for (int k = 0; k < 16; k++) we1r[k] = We1[k * HID + j];
        double be1_d = (double)be1[j];
        double msum = 0.0;
        for (int n = 0; n < NN_; n++) msum += (double)sm.m_s[n];
        msum = fmax(msum, 1.0);
        double pacc = 0.0;
        for (int n = 0; n < NN_; n++) {
            double pre = be1_d;
#pragma unroll
            for (int k = 0; k < 8; k++) pre = fma((double)sm.x_s[n][k], (double)we1r[k], pre);
#pragma unroll
            for (int k = 0; k < 8; k++) pre = fma((double)sm.y_s[n][k], (double)we1r[8 + k], pre);
            pacc += gelu_d(pre) * (double)sm.m_s[n];
        }
        sm.hb_ds[j] = pacc / msum;
    }
    __syncthreads();
    if (tid < 256) {
        int i = tid & 127, half = tid >> 7;
        double racc = 0.0;
        for (int jj = half * 128; jj < half * 128 + 128; jj++)
            racc = fma(sm.hb_ds[jj], (double)We2[jj * RD + i], racc);
        sm.scratch4[half][i] = racc;
    }
    __syncthreads();
    if (tid < RD) r_d[tid] = sm.scratch4[0][tid] + sm.scratch4[1][tid] + (double)be2[tid];
    __syncthreads();

    if (tid < 256) {                     // step-invariant drift-hidden -> LDS
        double hbr = (double)bb1[j];
        for (int k = 0; k < RD; k++)
            hbr = fma(r_d[k], (double)Wb1[(ZD + k) * HID + j], hbr);
        sm.hbt_s[j] = hbr;
        sm.wbt_s[j] = (double)Wb1[(ZD + RD) * HID + j];
    }
    __syncthreads();                     // r_d alias free after this

    // ---------------- main 50-step loop ----------------
    const double dt  = 1.0 / (double)NSTEPS;
    const double nsc = sqrt(2.0 * 1.0 * dt);

    // fused M+R mapping (constant per thread)
    const int mr_nn = tid >> 6, mr_yd = (tid >> 3) & 7, mr_q = tid & 7;

    for (int s = 0; s < NSTEPS; s++) {
        const double t = (double)s * dt;

        float nzf = 0.0f;
        if (tid < ZD) nzf = noise[((size_t)s * BB + b) * ZD + tid];

        // ---- phase 1: A drift-hidden partials + zdot quarter-partials ----
        {
            double a0 = 0.0;
            const int kb = q2 * 16;
            const float* wb1p = Wb1 + kb * HID + j;
#pragma unroll 8
            for (int kk = 0; kk < 16; kk++)
                a0 = fma(sm.z_ds[kb + kk], (double)wb1p[kk * HID], a0);
            sm.scratch4[q2][j] = a0;

            double zq0 = 0.0, zq1 = 0.0;
#pragma unroll
            for (int q = q2 * 4; q < q2 * 4 + 4; q++) {
                float4 wv = sm.wd1z4[j][q ^ (j & 15)];
                const int k = q * 4;
                zq0 = fma(sm.z_ds[k],     (double)wv.x, zq0);
                zq1 = fma(sm.z_ds[k + 1], (double)wv.y, zq1);
                zq0 = fma(sm.z_ds[k + 2], (double)wv.z, zq0);
                zq1 = fma(sm.z_ds[k + 3], (double)wv.w, zq1);
            }
            sm.pmgz[q2 * 256 + j] = zq0 + zq1;   // zdot partial (pmgz alias)
        }
        __syncthreads();
        // ---- phase 2: drift hidden gelu (256 threads) ----
        if (tid < 256) {
            double hacc = sm.hbt_s[j] + t * sm.wbt_s[j]
                        + sm.scratch4[0][j] + sm.scratch4[1][j]
                        + sm.scratch4[2][j] + sm.scratch4[3][j];
            sm.hb_ds[j] = gelu_d(hacc);
        }
        __syncthreads();
        // ---- drift out partials (no trailing barrier; consumed at update) ----
        {
            double acc = 0.0;
            const float* wb2p = Wb2 + (du_c * 16) * ZD + du_k;
#pragma unroll 8
            for (int i = 0; i < 16; i++)
                acc = fma(sm.hb_ds[du_c * 16 + i], (double)wb2p[i * ZD], acc);
            sm.bp_d[du_c][du_k] = acc;
        }

        // zpre from deduplicated zdot partials (pmgz alias)
        const double zpre = (double)sm.bd1_s[j]
            + ((sm.pmgz[j] + sm.pmgz[256 + j]) + (sm.pmgz[512 + j] + sm.pmgz[768 + j]));

        // ---- decode fwd+bwd: 8 tiles x 16 rows (4 rows/thread in F/B) ----
        double S = 0.0;
        const int rb = q2 * 4;
        float gp_r0, gp_r1, gp_r2, gp_r3;

        for (int tile = 0; tile < NTILES; tile++) {
            const int xb = tile * NT + rb;
            // F: rows 0,1
            {
                const float4 xa = *reinterpret_cast<const float4*>(&sm.x_s[xb + 0][0]);
                const float4 xxb = *reinterpret_cast<const float4*>(&sm.x_s[xb + 0][4]);
                const float4 xc = *reinterpret_cast<const float4*>(&sm.x_s[xb + 1][0]);
                const float4 xd = *reinterpret_cast<const float4*>(&sm.x_s[xb + 1][4]);
                double p0 = zpre, p1 = zpre;
                p0 = fma((double)xa.x, (double)wd1x[0], p0);
                p0 = fma((double)xa.y, (double)wd1x[1], p0);
                p0 = fma((double)xa.z, (double)wd1x[2], p0);
                p0 = fma((double)xa.w, (double)wd1x[3], p0);
                p0 = fma((double)xxb.x, (double)wd1x[4], p0);
                p0 = fma((double)xxb.y, (double)wd1x[5], p0);
                p0 = fma((double)xxb.z, (double)wd1x[6], p0);
                p0 = fma((double)xxb.w, (double)wd1x[7], p0);
                p1 = fma((double)xc.x, (double)wd1x[0], p1);
                p1 = fma((double)xc.y, (double)wd1x[1], p1);
                p1 = fma((double)xc.z, (double)wd1x[2], p1);
                p1 = fma((double)xc.w, (double)wd1x[3], p1);
                p1 = fma((double)xd.x, (double)wd1x[4], p1);
                p1 = fma((double)xd.y, (double)wd1x[5], p1);
                p1 = fma((double)xd.z, (double)wd1x[6], p1);
                p1 = fma((double)xd.w, (double)wd1x[7], p1);
                double h0, g0, h1, g1;
                gelu_both_d(p0, h0, g0);
                gelu_both_d(p1, h1, g1);
                sm.h_t[rb + 0][j] = h0; gp_r0 = (float)g0;
                sm.h_t[rb + 1][j] = h1; gp_r1 = (float)g1;
            }
            // F: rows 2,3
            {
                const float4 xa = *reinterpret_cast<const float4*>(&sm.x_s[xb + 2][0]);
                const float4 xxb = *reinterpret_cast<const float4*>(&sm.x_s[xb + 2][4]);
                const float4 xc = *reinterpret_cast<const float4*>(&sm.x_s[xb + 3][0]);
                const float4 xd = *reinterpret_cast<const float4*>(&sm.x_s[xb + 3][4]);
                double p0 = zpre, p1 = zpre;
                p0 = fma((double)xa.x, (double)wd1x[0], p0);
                p0 = fma((double)xa.y, (double)wd1x[1], p0);
                p0 = fma((double)xa.z, (double)wd1x[2], p0);
                p0 = fma((double)xa.w, (double)wd1x[3], p0);
                p0 = fma((double)xxb.x, (double)wd1x[4], p0);
                p0 = fma((double)xxb.y, (double)wd1x[5], p0);
                p0 = fma((double)xxb.z, (double)wd1x[6], p0);
                p0 = fma((double)xxb.w, (double)wd1x[7], p0);
                p1 = fma((double)xc.x, (double)wd1x[0], p1);
                p1 = fma((double)xc.y, (double)wd1x[1], p1);
                p1 = fma((double)xc.z, (double)wd1x[2], p1);
                p1 = fma((double)xc.w, (double)wd1x[3], p1);
                p1 = fma((double)xd.x, (double)wd1x[4], p1);
                p1 = fma((double)xd.y, (double)wd1x[5], p1);
                p1 = fma((double)xd.z, (double)wd1x[6], p1);
                p1 = fma((double)xd.w, (double)wd1x[7], p1);
                double h0, g0, h1, g1;
                gelu_both_d(p0, h0, g0);
                gelu_both_d(p1, h1, g1);
                sm.h_t[rb + 2][j] = h0; gp_r2 = (float)g0;
                sm.h_t[rb + 3][j] = h1; gp_r3 = (float)g1;
            }
            __syncthreads();
            // fused M+R: thread (nn,yd,q) dots one j-octant; rotation dd=(d+q)
            // -> h banks 4((nn+d+q)&7) distinct per q-group (broadcast over yd);
            // w scalar reads from wd2tq: bank (8q+yd+2dd) pairwise-distinct.
            {
                const double2* hrow =
                    reinterpret_cast<const double2*>(&sm.h_t[mr_nn][mr_q * 32]);
                const float* wrow = &sm.wd2tq[mr_q][mr_yd][0];
                double a0 = 0.0, a1 = 0.0;
#pragma unroll 8
                for (int d = 0; d < 16; d++) {
                    const int dd = (d + mr_q) & 15;
                    double2 hv = hrow[dd];
                    const float wx = wrow[2 * dd];
                    const float wy = wrow[2 * dd + 1];
                    a0 = fma(hv.x, (double)wx, a0);
                    a1 = fma(hv.y, (double)wy, a1);
                }
                double v = a0 + a1;
                v += __shfl_xor(v, 1);
                v += __shfl_xor(v, 2);
                v += __shfl_xor(v, 4);
                if (mr_q == 0) {
                    const int row = tile * NT + mr_nn;
                    double mu = v + sm.bd2_d[mr_yd];
                    sm.res_r[mr_nn][mr_yd] =
                        4.0 * t * (mu - (double)sm.y_s[row][mr_yd])
                                * (double)sm.m_s[row];
                }
            }
            __syncthreads();
            // B: S += dpre over this thread's 4 rows (flows into next F)
            {
                const float w0 = sm.wd2t_f[0][j], w1 = sm.wd2t_f[1][j];
                const float w2 = sm.wd2t_f[2][j], w3 = sm.wd2t_f[3][j];
                const float w4 = sm.wd2t_f[4][j], w5 = sm.wd2t_f[5][j];
                const float w6 = sm.wd2t_f[6][j], w7 = sm.wd2t_f[7][j];
                const double2* rr0 = reinterpret_cast<const double2*>(&sm.res_r[rb + 0][0]);
                const double2* rr1 = reinterpret_cast<const double2*>(&sm.res_r[rb + 1][0]);
                const double2* rr2 = reinterpret_cast<const double2*>(&sm.res_r[rb + 2][0]);
                const double2* rr3 = reinterpret_cast<const double2*>(&sm.res_r[rb + 3][0]);
                double2 a0, a1, a2, a3;
                a0 = rr0[0]; a1 = rr0[1]; a2 = rr0[2]; a3 = rr0[3];
                double dh0 = a0.x * (double)w0 + a0.y * (double)w1
                           + a1.x * (double)w2 + a1.y * (double)w3
                           + a2.x * (double)w4 + a2.y * (double)w5
                           + a3.x * (double)w6 + a3.y * (double)w7;
                S = fma(dh0, (double)gp_r0, S);
                a0 = rr1[0]; a1 = rr1[1]; a2 = rr1[2]; a3 = rr1[3];
                double dh1 = a0.x * (double)w0 + a0.y * (double)w1
                           + a1.x * (double)w2 + a1.y * (double)w3
                           + a2.x * (double)w4 + a2.y * (double)w5
                           + a3.x * (double)w6 + a3.y * (double)w7;
                S = fma(dh1, (double)gp_r1, S);
                a0 = rr2[0]; a1 = rr2[1]; a2 = rr2[2]; a3 = rr2[3];
                double dh2 = a0.x * (double)w0 + a0.y * (double)w1
                           + a1.x * (double)w2 + a1.y * (double)w3
                           + a2.x * (double)w4 + a2.y * (double)w5
                           + a3.x * (double)w6 + a3.y * (double)w7;
                S = fma(dh2, (double)gp_r2, S);
                a0 = rr3[0]; a1 = rr3[1]; a2 = rr3[2]; a3 = rr3[3];
                double dh3 = a0.x * (double)w0 + a0.y * (double)w1
                           + a1.x * (double)w2 + a1.y * (double)w3
                           + a2.x * (double)w4 + a2.y * (double)w5
                           + a3.x * (double)w6 + a3.y * (double)w7;
                S = fma(dh3, (double)gp_r3, S);
            }
        }

        // ---- gradient matvec ----
        sm.scratch4[q2][j] = S;
        __syncthreads();
        {
            const int k = du_k, c = du_c;        // 16 c-groups of 16 jj
            const int qk = k >> 2, ck = k & 3;
            double acc = 0.0;
#pragma unroll 8
            for (int i = 0; i < 16; i++) {
                const int jj = c * 16 + i;
                const float w = reinterpret_cast<const float*>(&sm.wd1z4[jj][0])
                                    [4 * (qk ^ (jj & 15)) + ck];
                const double sv = sm.scratch4[0][jj] + sm.scratch4[1][jj]
                                + sm.scratch4[2][jj] + sm.scratch4[3][jj];
                acc = fma(sv, (double)w, acc);
            }
            sm.pmgz[c * 64 + k] = acc;
        }
        __syncthreads();
        // ---- z update ----
        if (tid < ZD) {
            double gsum = sm.z_ds[tid];
#pragma unroll
            for (int c = 0; c < 16; c++) gsum += sm.pmgz[c * 64 + tid];
            gsum = fmin(fmax(gsum, -100.0), 100.0);
            double bdr = sm.bb2_d[tid];
#pragma unroll
            for (int c = 0; c < 16; c++) bdr += sm.bp_d[c][tid];
            sm.z_ds[tid] = sm.z_ds[tid] + (bdr - gsum) * dt + nsc * (double)nzf;
        }
        __syncthreads();
    }

    if (tid < ZD) out[(size_t)b * ZD + tid] = (float)sm.z_ds[tid];
}

extern "C" void kernel_launch(void* const* d_in, const int* in_sizes, int n_in,
                              void* d_out, int out_size, void* d_ws, size_t ws_size,
                              hipStream_t stream) {
    const float* x_ctx = (const float*)d_in[0];
    const float* y_ctx = (const float*)d_in[1];
    const float* maskp = (const float*)d_in[2];
    const float* z0    = (const float*)d_in[3];
    const float* noise = (const float*)d_in[4];
    const float* We1   = (const float*)d_in[5];
    const float* be1   = (const float*)d_in[6];
    const float* We2   = (const float*)d_in[7];
    const float* be2   = (const float*)d_in[8];
    const float* Wd1   = (const float*)d_in[9];
    const float* bd1   = (const float*)d_in[10];
    const float* Wd2   = (const float*)d_in[11];
    const float* bd2   = (const float*)d_in[12];
    const float* Wb1   = (const float*)d_in[13];
    const float* bb1   = (const float*)d_in[14];
    const float* Wb2   = (const float*)d_in[15];
    const float* bb2   = (const float*)d_in[16];
    float* out = (float*)d_out;

    (void)hipFuncSetAttribute((const void*)nets_sampler_kernel,
                              hipFuncAttributeMaxDynamicSharedMemorySize,
                              (int)sizeof(Smem));

    nets_sampler_kernel<<<BB, TPB, sizeof(Smem), stream>>>(
        x_ctx, y_ctx, maskp, z0, noise,
        We1, be1, We2, be2, Wd1, bd1, Wd2, bd2, Wb1, bb1, Wb2, bb2, out);
}

// Round 12
// 1730.883 us; speedup vs baseline: 1.1134x; 1.1134x over previous
//
#include <hip/hip_runtime.h>
#include <math.h>

#define BB    256
#define NN_   128
#define ZD    64
#define RD    128
#define HID   256
#define NSTEPS 50
#define NT    16
#define NTILES 8
#define TPB   1024
#define PADD  258   // f64 row stride

// ---------- fast f64-accuracy exp/sigmoid/gelu (no libm, no f64 divide) ----------
__device__ __forceinline__ double fast_exp_d(double x) {
    const double L2E   = 1.44269504088896340736;
    const double LN2HI = 6.93147180369123816490e-01;
    const double LN2LO = 1.90821492927058770002e-10;
    const double MAGIC = 6755399441055744.0;           // 1.5*2^52
    double vn = fma(x, L2E, MAGIC);
    int ni = __double2loint(vn);
    double n = vn - MAGIC;
    double r = fma(n, -LN2HI, x);
    r = fma(n, -LN2LO, r);
    double p = 2.50521083854417187751e-08;
    p = fma(p, r, 2.75573192239858906526e-07);
    p = fma(p, r, 2.75573192239858906526e-06);
    p = fma(p, r, 2.48015873015873015873e-05);
    p = fma(p, r, 1.98412698412698412698e-04);
    p = fma(p, r, 1.38888888888888888889e-03);
    p = fma(p, r, 8.33333333333333333333e-03);
    p = fma(p, r, 4.16666666666666666667e-02);
    p = fma(p, r, 1.66666666666666666667e-01);
    p = fma(p, r, 0.5);
    p = fma(p, r, 1.0);
    p = fma(p, r, 1.0);
    return p * __hiloint2double((1023 + ni) << 20, 0);
}

__device__ __forceinline__ double sigmoid_d(double w) {
    double wc = fmin(fmax(w, -60.0), 60.0);
    double e = fast_exp_d(-wc);
    double d = 1.0 + e;
    float r0 = __builtin_amdgcn_rcpf((float)d);
    double y = (double)r0;
    y = fma(y, fma(-d, y, 1.0), y);
    y = fma(y, fma(-d, y, 1.0), y);
    return y;
}

__device__ __forceinline__ double gelu_d(double x) {
    const double c2 = 1.59576912160573071176;
    double w = c2 * x * fma(0.044715, x * x, 1.0);
    return x * sigmoid_d(w);
}

__device__ __forceinline__ void gelu_both_d(double x, double& h, double& gp) {
    const double c  = 0.79788456080286535588;
    const double a  = 0.044715;
    double x2 = x * x;
    double w  = (2.0 * c) * x * fma(a, x2, 1.0);
    double hp = sigmoid_d(w);
    h = x * hp;
    double s = hp * (1.0 - hp);
    gp = fma(x * s, (2.0 * c) * fma(3.0 * a, x2, 1.0), hp);
}

// ---------- dynamic LDS layout (~146 KB) ----------
struct Smem {
    double h_t[NT][PADD];        // decode hidden tile (f64)      33.0 KB
    float  wd2t_f[8][PADD];      // Wd2^T (f32 exact)              8.3 KB
    double z_ds[ZD];
    double hb_ds[HID];           // pooled / drift hidden
    double scratch4[4][HID];     // A-partials / S-partials        8 KB
    double pmgz[1024];           // zdot parts / mu parts / gzp    8 KB (aliased)
    double res_r[NT][8];         // residual tile / r_d[128] alias
    double bp_d[16][ZD];         // drift-out partials             8 KB
    double bd2_d[8];
    double bb2_d[ZD];
    double hbt_s[HID];           // step-invariant drift-hidden base
    double wbt_s[HID];           // Wb1 t-row
    float  bd1_s[HID];
    float  x_s[NN_][8];
    float  y_s[NN_][8];
    float  m_s[NN_];
    __align__(16) float4 wd1z4[HID][16];   // Wd1 z-block, swizzled  64 KB
};

// r10/r11 lesson: both fused-M+R bank layouts CONFLICTED (52.8M, 105M cycles
// vs r9's 393K) — hand-derived swizzles for that pattern are unreliable.
// This round: exact r9 phase structure (measured conflict-free, 1782 us)
// + the one verified-safe improvement: zdot dedup (phase-1 quarter-partials
// aliased into pmgz; same per-instruction LDS pattern, 4x fewer reads).
__global__ void __launch_bounds__(TPB)
nets_sampler_kernel(
    const float* __restrict__ x_ctx, const float* __restrict__ y_ctx,
    const float* __restrict__ mask,  const float* __restrict__ z0,
    const float* __restrict__ noise,
    const float* __restrict__ We1, const float* __restrict__ be1,
    const float* __restrict__ We2, const float* __restrict__ be2,
    const float* __restrict__ Wd1, const float* __restrict__ bd1,
    const float* __restrict__ Wd2, const float* __restrict__ bd2,
    const float* __restrict__ Wb1, const float* __restrict__ bb1,
    const float* __restrict__ Wb2, const float* __restrict__ bb2,
    float* __restrict__ out)
{
    extern __shared__ char smem_raw[];
    Smem& sm = *reinterpret_cast<Smem*>(smem_raw);

    const int b   = blockIdx.x;
    const int tid = threadIdx.x;
    const int j   = tid & 255;       // hidden column
    const int q2  = tid >> 8;        // quarter (0..3)
    const int du_k = tid & 63, du_c = tid >> 6;   // 64x16 partition
    double* r_d = &sm.res_r[0][0];   // alias (pre-loop only)

    // ---------------- loads ----------------
    if (tid < 256) {
        reinterpret_cast<float4*>(&sm.x_s[0][0])[tid] =
            reinterpret_cast<const float4*>(x_ctx + (size_t)b * NN_ * 8)[tid];
        reinterpret_cast<float4*>(&sm.y_s[0][0])[tid] =
            reinterpret_cast<const float4*>(y_ctx + (size_t)b * NN_ * 8)[tid];
        sm.bd1_s[j] = bd1[j];
        float4 a0 = reinterpret_cast<const float4*>(Wd2 + (size_t)j * 8)[0];
        float4 a1 = reinterpret_cast<const float4*>(Wd2 + (size_t)j * 8)[1];
        sm.wd2t_f[0][j] = a0.x; sm.wd2t_f[1][j] = a0.y;
        sm.wd2t_f[2][j] = a0.z; sm.wd2t_f[3][j] = a0.w;
        sm.wd2t_f[4][j] = a1.x; sm.wd2t_f[5][j] = a1.y;
        sm.wd2t_f[6][j] = a1.z; sm.wd2t_f[7][j] = a1.w;
    }
    if (tid < NN_) sm.m_s[tid] = mask[(size_t)b * NN_ + tid];
    if (tid < ZD) {
        sm.z_ds[tid]  = (double)z0[(size_t)b * ZD + tid];
        sm.bb2_d[tid] = (double)bb2[tid];
    }
    if (tid < 8) sm.bd2_d[tid] = (double)bd2[tid];

    // Wd1 z-block -> swizzled LDS
#pragma unroll
    for (int kk = 0; kk < 16; kk++) {
        const int k = q2 * 16 + kk;
        const float v = Wd1[(8 + k) * HID + j];
        reinterpret_cast<float*>(&sm.wd1z4[j][0])[4 * ((k >> 2) ^ (j & 15)) + (k & 3)] = v;
    }

    float wd1x[8];                       // Wd1 x-rows, column j (exact f32)
#pragma unroll
    for (int k = 0; k < 8; k++) wd1x[k] = Wd1[k * HID + j];

    __syncthreads();

    // ---------------- encoder (once, f64) ----------------
    if (tid < 256) {
        float we1r[16];
#pragma unroll
        for (int k = 0; k < 16; k++) we1r[k] = We1[k * HID + j];
        double be1_d = (double)be1[j];
        double msum = 0.0;
        for (int n = 0; n < NN_; n++) msum += (double)sm.m_s[n];
        msum = fmax(msum, 1.0);
        double pacc = 0.0;
        for (int n = 0; n < NN_; n++) {
            double pre = be1_d;
#pragma unroll
            for (int k = 0; k < 8; k++) pre = fma((double)sm.x_s[n][k], (double)we1r[k], pre);
#pragma unroll
            for (int k = 0; k < 8; k++) pre = fma((double)sm.y_s[n][k], (double)we1r[8 + k], pre);
            pacc += gelu_d(pre) * (double)sm.m_s[n];
        }
        sm.hb_ds[j] = pacc / msum;
    }
    __syncthreads();
    if (tid < 256) {
        int i = tid & 127, half = tid >> 7;
        double racc = 0.0;
        for (int jj = half * 128; jj < half * 128 + 128; jj++)
            racc = fma(sm.hb_ds[jj], (double)We2[jj * RD + i], racc);
        sm.scratch4[half][i] = racc;
    }
    __syncthreads();
    if (tid < RD) r_d[tid] = sm.scratch4[0][tid] + sm.scratch4[1][tid] + (double)be2[tid];
    __syncthreads();

    if (tid < 256) {                     // step-invariant drift-hidden -> LDS
        double hbr = (double)bb1[j];
        for (int k = 0; k < RD; k++)
            hbr = fma(r_d[k], (double)Wb1[(ZD + k) * HID + j], hbr);
        sm.hbt_s[j] = hbr;
        sm.wbt_s[j] = (double)Wb1[(ZD + RD) * HID + j];
    }
    __syncthreads();                     // r_d alias free after this

    // ---------------- main 50-step loop ----------------
    const double dt  = 1.0 / (double)NSTEPS;
    const double nsc = sqrt(2.0 * 1.0 * dt);

    for (int s = 0; s < NSTEPS; s++) {
        const double t = (double)s * dt;

        float nzf = 0.0f;
        if (tid < ZD) nzf = noise[((size_t)s * BB + b) * ZD + tid];

        // ---- phase 1: A drift-hidden partials + zdot quarter-partials ----
        {
            double a0 = 0.0;
            const int kb = q2 * 16;
            const float* wb1p = Wb1 + kb * HID + j;
#pragma unroll 8
            for (int kk = 0; kk < 16; kk++)
                a0 = fma(sm.z_ds[kb + kk], (double)wb1p[kk * HID], a0);
            sm.scratch4[q2][j] = a0;

            double zq0 = 0.0, zq1 = 0.0;
#pragma unroll
            for (int q = q2 * 4; q < q2 * 4 + 4; q++) {
                float4 wv = sm.wd1z4[j][q ^ (j & 15)];
                const int k = q * 4;
                zq0 = fma(sm.z_ds[k],     (double)wv.x, zq0);
                zq1 = fma(sm.z_ds[k + 1], (double)wv.y, zq1);
                zq0 = fma(sm.z_ds[k + 2], (double)wv.z, zq0);
                zq1 = fma(sm.z_ds[k + 3], (double)wv.w, zq1);
            }
            sm.pmgz[q2 * 256 + j] = zq0 + zq1;   // zdot partial (pmgz alias)
        }
        __syncthreads();
        // ---- phase 2: drift hidden gelu (256 threads) ----
        if (tid < 256) {
            double hacc = sm.hbt_s[j] + t * sm.wbt_s[j]
                        + sm.scratch4[0][j] + sm.scratch4[1][j]
                        + sm.scratch4[2][j] + sm.scratch4[3][j];
            sm.hb_ds[j] = gelu_d(hacc);
        }
        __syncthreads();
        // ---- drift out partials (no trailing barrier; consumed at update) ----
        {
            double acc = 0.0;
            const float* wb2p = Wb2 + (du_c * 16) * ZD + du_k;
#pragma unroll 8
            for (int i = 0; i < 16; i++)
                acc = fma(sm.hb_ds[du_c * 16 + i], (double)wb2p[i * ZD], acc);
            sm.bp_d[du_c][du_k] = acc;
        }

        // zpre from deduplicated zdot partials (read BEFORE M overwrites pmgz)
        const double zpre = (double)sm.bd1_s[j]
            + ((sm.pmgz[j] + sm.pmgz[256 + j]) + (sm.pmgz[512 + j] + sm.pmgz[768 + j]));

        // ---- decode fwd+bwd: 8 tiles x 16 rows (4 rows/thread in F/B) ----
        double S = 0.0;
        const int rb = q2 * 4;
        float gp_r0, gp_r1, gp_r2, gp_r3;

        for (int tile = 0; tile < NTILES; tile++) {
            const int xb = tile * NT + rb;
            // F: rows 0,1
            {
                const float4 xa = *reinterpret_cast<const float4*>(&sm.x_s[xb + 0][0]);
                const float4 xxb = *reinterpret_cast<const float4*>(&sm.x_s[xb + 0][4]);
                const float4 xc = *reinterpret_cast<const float4*>(&sm.x_s[xb + 1][0]);
                const float4 xd = *reinterpret_cast<const float4*>(&sm.x_s[xb + 1][4]);
                double p0 = zpre, p1 = zpre;
                p0 = fma((double)xa.x, (double)wd1x[0], p0);
                p0 = fma((double)xa.y, (double)wd1x[1], p0);
                p0 = fma((double)xa.z, (double)wd1x[2], p0);
                p0 = fma((double)xa.w, (double)wd1x[3], p0);
                p0 = fma((double)xxb.x, (double)wd1x[4], p0);
                p0 = fma((double)xxb.y, (double)wd1x[5], p0);
                p0 = fma((double)xxb.z, (double)wd1x[6], p0);
                p0 = fma((double)xxb.w, (double)wd1x[7], p0);
                p1 = fma((double)xc.x, (double)wd1x[0], p1);
                p1 = fma((double)xc.y, (double)wd1x[1], p1);
                p1 = fma((double)xc.z, (double)wd1x[2], p1);
                p1 = fma((double)xc.w, (double)wd1x[3], p1);
                p1 = fma((double)xd.x, (double)wd1x[4], p1);
                p1 = fma((double)xd.y, (double)wd1x[5], p1);
                p1 = fma((double)xd.z, (double)wd1x[6], p1);
                p1 = fma((double)xd.w, (double)wd1x[7], p1);
                double h0, g0, h1, g1;
                gelu_both_d(p0, h0, g0);
                gelu_both_d(p1, h1, g1);
                sm.h_t[rb + 0][j] = h0; gp_r0 = (float)g0;
                sm.h_t[rb + 1][j] = h1; gp_r1 = (float)g1;
            }
            // F: rows 2,3
            {
                const float4 xa = *reinterpret_cast<const float4*>(&sm.x_s[xb + 2][0]);
                const float4 xxb = *reinterpret_cast<const float4*>(&sm.x_s[xb + 2][4]);
                const float4 xc = *reinterpret_cast<const float4*>(&sm.x_s[xb + 3][0]);
                const float4 xd = *reinterpret_cast<const float4*>(&sm.x_s[xb + 3][4]);
                double p0 = zpre, p1 = zpre;
                p0 = fma((double)xa.x, (double)wd1x[0], p0);
                p0 = fma((double)xa.y, (double)wd1x[1], p0);
                p0 = fma((double)xa.z, (double)wd1x[2], p0);
                p0 = fma((double)xa.w, (double)wd1x[3], p0);
                p0 = fma((double)xxb.x, (double)wd1x[4], p0);
                p0 = fma((double)xxb.y, (double)wd1x[5], p0);
                p0 = fma((double)xxb.z, (double)wd1x[6], p0);
                p0 = fma((double)xxb.w, (double)wd1x[7], p0);
                p1 = fma((double)xc.x, (double)wd1x[0], p1);
                p1 = fma((double)xc.y, (double)wd1x[1], p1);
                p1 = fma((double)xc.z, (double)wd1x[2], p1);
                p1 = fma((double)xc.w, (double)wd1x[3], p1);
                p1 = fma((double)xd.x, (double)wd1x[4], p1);
                p1 = fma((double)xd.y, (double)wd1x[5], p1);
                p1 = fma((double)xd.z, (double)wd1x[6], p1);
                p1 = fma((double)xd.w, (double)wd1x[7], p1);
                double h0, g0, h1, g1;
                gelu_both_d(p0, h0, g0);
                gelu_both_d(p1, h1, g1);
                sm.h_t[rb + 2][j] = h0; gp_r2 = (float)g0;
                sm.h_t[rb + 3][j] = h1; gp_r3 = (float)g1;
            }
            __syncthreads();
            // M: mu partials over j-eighths (r9 pattern — measured conflict-free)
            {
                const int q = tid >> 7, pair = tid & 127;
                const int nn = pair >> 3, yd = pair & 7;
                const double2* hrow = reinterpret_cast<const double2*>(&sm.h_t[nn][q * 32]);
                const float2*  wrow = reinterpret_cast<const float2*>(&sm.wd2t_f[yd][q * 32]);
                double a0 = 0.0, a1 = 0.0;
#pragma unroll 8
                for (int i = 0; i < 16; i++) {
                    double2 hv = hrow[i];
                    float2  wv = wrow[i];
                    a0 = fma(hv.x, (double)wv.x, a0);
                    a1 = fma(hv.y, (double)wv.y, a1);
                }
                sm.pmgz[q * 128 + pair] = a0 + a1;
            }
            __syncthreads();
            // R: residual
            if (tid < 128) {
                const int nn = tid >> 3, yd = tid & 7;
                double mu = sm.bd2_d[yd];
#pragma unroll
                for (int q = 0; q < 8; q++) mu += sm.pmgz[q * 128 + tid];
                sm.res_r[nn][yd] = 4.0 * t * (mu - (double)sm.y_s[tile * NT + nn][yd])
                                           * (double)sm.m_s[tile * NT + nn];
            }
            __syncthreads();
            // B: S += dpre over this thread's 4 rows (flows into next F)
            {
                const float w0 = sm.wd2t_f[0][j], w1 = sm.wd2t_f[1][j];
                const float w2 = sm.wd2t_f[2][j], w3 = sm.wd2t_f[3][j];
                const float w4 = sm.wd2t_f[4][j], w5 = sm.wd2t_f[5][j];
                const float w6 = sm.wd2t_f[6][j], w7 = sm.wd2t_f[7][j];
                const double2* rr0 = reinterpret_cast<const double2*>(&sm.res_r[rb + 0][0]);
                const double2* rr1 = reinterpret_cast<const double2*>(&sm.res_r[rb + 1][0]);
                const double2* rr2 = reinterpret_cast<const double2*>(&sm.res_r[rb + 2][0]);
                const double2* rr3 = reinterpret_cast<const double2*>(&sm.res_r[rb + 3][0]);
                double2 a0, a1, a2, a3;
                a0 = rr0[0]; a1 = rr0[1]; a2 = rr0[2]; a3 = rr0[3];
                double dh0 = a0.x * (double)w0 + a0.y * (double)w1
                           + a1.x * (double)w2 + a1.y * (double)w3
                           + a2.x * (double)w4 + a2.y * (double)w5
                           + a3.x * (double)w6 + a3.y * (double)w7;
                S = fma(dh0, (double)gp_r0, S);
                a0 = rr1[0]; a1 = rr1[1]; a2 = rr1[2]; a3 = rr1[3];
                double dh1 = a0.x * (double)w0 + a0.y * (double)w1
                           + a1.x * (double)w2 + a1.y * (double)w3
                           + a2.x * (double)w4 + a2.y * (double)w5
                           + a3.x * (double)w6 + a3.y * (double)w7;
                S = fma(dh1, (double)gp_r1, S);
                a0 = rr2[0]; a1 = rr2[1]; a2 = rr2[2]; a3 = rr2[3];
                double dh2 = a0.x * (double)w0 + a0.y * (double)w1
                           + a1.x * (double)w2 + a1.y * (double)w3
                           + a2.x * (double)w4 + a2.y * (double)w5
                           + a3.x * (double)w6 + a3.y * (double)w7;
                S = fma(dh2, (double)gp_r2, S);
                a0 = rr3[0]; a1 = rr3[1]; a2 = rr3[2]; a3 = rr3[3];
                double dh3 = a0.x * (double)w0 + a0.y * (double)w1
                           + a1.x * (double)w2 + a1.y * (double)w3
                           + a2.x * (double)w4 + a2.y * (double)w5
                           + a3.x * (double)w6 + a3.y * (double)w7;
                S = fma(dh3, (double)gp_r3, S);
            }
        }

        // ---- gradient matvec ----
        sm.scratch4[q2][j] = S;
        __syncthreads();
        {
            const int k = du_k, c = du_c;        // 16 c-groups of 16 jj
            const int qk = k >> 2, ck = k & 3;
            double acc = 0.0;
#pragma unroll 8
            for (int i = 0; i < 16; i++) {
                const int jj = c * 16 + i;
                const float w = reinterpret_cast<const float*>(&sm.wd1z4[jj][0])
                                    [4 * (qk ^ (jj & 15)) + ck];
                const double sv = sm.scratch4[0][jj] + sm.scratch4[1][jj]
                                + sm.scratch4[2][jj] + sm.scratch4[3][jj];
                acc = fma(sv, (double)w, acc);
            }
            sm.pmgz[c * 64 + k] = acc;
        }
        __syncthreads();
        // ---- z update ----
        if (tid < ZD) {
            double gsum = sm.z_ds[tid];
#pragma unroll
            for (int c = 0; c < 16; c++) gsum += sm.pmgz[c * 64 + tid];
            gsum = fmin(fmax(gsum, -100.0), 100.0);
            double bdr = sm.bb2_d[tid];
#pragma unroll
            for (int c = 0; c < 16; c++) bdr += sm.bp_d[c][tid];
            sm.z_ds[tid] = sm.z_ds[tid] + (bdr - gsum) * dt + nsc * (double)nzf;
        }
        __syncthreads();
    }

    if (tid < ZD) out[(size_t)b * ZD + tid] = (float)sm.z_ds[tid];
}

extern "C" void kernel_launch(void* const* d_in, const int* in_sizes, int n_in,
                              void* d_out, int out_size, void* d_ws, size_t ws_size,
                              hipStream_t stream) {
    const float* x_ctx = (const float*)d_in[0];
    const float* y_ctx = (const float*)d_in[1];
    const float* maskp = (const float*)d_in[2];
    const float* z0    = (const float*)d_in[3];
    const float* noise = (const float*)d_in[4];
    const float* We1   = (const float*)d_in[5];
    const float* be1   = (const float*)d_in[6];
    const float* We2   = (const float*)d_in[7];
    const float* be2   = (const float*)d_in[8];
    const float* Wd1   = (const float*)d_in[9];
    const float* bd1   = (const float*)d_in[10];
    const float* Wd2   = (const float*)d_in[11];
    const float* bd2   = (const float*)d_in[12];
    const float* Wb1   = (const float*)d_in[13];
    const float* bb1   = (const float*)d_in[14];
    const float* Wb2   = (const float*)d_in[15];
    const float* bb2   = (const float*)d_in[16];
    float* out = (float*)d_out;

    (void)hipFuncSetAttribute((const void*)nets_sampler_kernel,
                              hipFuncAttributeMaxDynamicSharedMemorySize,
                              (int)sizeof(Smem));

    nets_sampler_kernel<<<BB, TPB, sizeof(Smem), stream>>>(
        x_ctx, y_ctx, maskp, z0, noise,
        We1, be1, We2, be2, Wd1, bd1, Wd2, bd2, Wb1, bb1, Wb2, bb2, out);
}